// Round 16
// baseline (208.554 us; speedup 1.0000x reference)
//
#include <hip/hip_runtime.h>
#include <math.h>

#pragma clang fp contract(off)

#define NXP   8192
#define GROUP 8      // 8 lanes per x-point; lane l owns terms k = l + 8s
#define CPN   16     // 16 terms per lane
#define NITER 40

// DPP helpers (VALU pipe). quad_perm xor1/xor2 for the 4-acc combine tree;
// row_shl:4 pulls lane l+4's value (within a row of 16 -> valid for each
// 8-lane group's low quad).
template <int CTRL>
__device__ __forceinline__ float dpp_mov(float v) {
    return __int_as_float(__builtin_amdgcn_update_dpp(
        0, __float_as_int(v), CTRL, 0xF, 0xF, true));
}
template <int CTRL>
__device__ __forceinline__ float qxor_add(float v) { return v + dpp_mov<CTRL>(v); }
#define RED4(v) do {                         \
    v = qxor_add<0xB1>(v);  /* quad xor 1 */ \
    v = qxor_add<0x4E>(v);  /* quad xor 2 */ \
} while (0)
#define PULL4(v) dpp_mov<0x104>(v)   /* row_shl:4 -> lane l gets lane l+4 */

// Correctly-rounded f32 divide for NORMAL-range operands (Markstein):
// bit-identical to IEEE a/b in our operand range; no s_setreg mode toggles.
__device__ __forceinline__ float div_ieee(float a, float b) {
    float r = __builtin_amdgcn_rcpf(b);
    float e = __builtin_fmaf(-b, r, 1.0f);
    r = __builtin_fmaf(e, r, r);
    e = __builtin_fmaf(-b, r, 1.0f);
    r = __builtin_fmaf(e, r, r);          // r ~ 1/b to ~0.5 ulp
    float q = a * r;
    float res = __builtin_fmaf(-b, q, a); // exact residual
    return __builtin_fmaf(res, r, q);     // correctly-rounded quotient
}

// numpy npy_cdivf (Smith), numerator (nr + 0i), branchless, nr > 0.
__device__ __forceinline__ void cdiv_nr(float nr, float dr, float di,
                                        float& qr, float& qi) {
    bool sw  = fabsf(di) > fabsf(dr);     // false -> numpy branch A (|dr|>=|di|)
    float u  = sw ? di : dr;
    float v  = sw ? dr : di;
    float rat = div_ieee(v, u);
    float w   = v * rat;
    float scl = div_ieee(1.0f, u + w);
    float t1  = nr * rat;
    float qrn = sw ? t1 : nr;             // A: nr        B: nr*rat
    float qin = sw ? nr : t1;             // A: nr*rat    B: nr
    qr = qrn * scl;
    qi = -qin * scl;                      // neg folds into mul modifier; ±0-safe
}

__global__ __launch_bounds__(128) void wesper_kernel(
    const float* __restrict__ x,
    const float* __restrict__ d,
    const float* __restrict__ wd,
    const float* __restrict__ tau,
    const float* __restrict__ wt,
    float* __restrict__ out)
{
#pragma clang fp contract(off)
    const int tid = threadIdx.x;
    const int L   = tid & (GROUP - 1);           // 0..7
    const int gid = blockIdx.x * (blockDim.x / GROUP) + (tid >> 3);

    // lane l owns coefficient indices k = l + 8s, s = 0..15.
    // numpy complex accumulator A (A=0..3) sums terms k = A + 4t in t-order:
    //   t even (=2s): k = A + 8s   -> lane A's q[s]
    //   t odd (=2s+1): k = A+4+8s  -> lane A+4's q[s]  (pulled via DPP row_shl:4)
    float tauC[CPN], wttC[CPN], wtC[CPN], cdC[CPN], wddC[CPN];
    #pragma unroll
    for (int s = 0; s < CPN; ++s) {
        int k = L + (s << 3);
        float tk = tau[k], wk = wt[k];
        tauC[s] = tk;
        wttC[s] = wk * tk;      // wt_tau (one f32 round)
        wtC[s]  = wk;
        float dj = d[k];
        cdC[s]  = 0.5f * dj;    // c*d (exact halving)
        wddC[s] = wd[k] * dj;   // wd_d (one f32 round)
    }
    const float xv = x[gid];

    // m0 = np.sum(wd*d): REAL pairwise, 8 accumulators stride 8 == our lanes.
    // combine ((r0+r1)+(r2+r3)) + ((r4+r5)+(r6+r7)): quad xor1+xor2, then xor4.
    float m0 = 0.0f;
    #pragma unroll
    for (int s = 0; s < CPN; ++s)
        m0 = (s == 0) ? wddC[s] : (m0 + wddC[s]);
    RED4(m0);
    m0 += __shfl_xor(m0, 4, 64);   // cross-quad combine (all 8 lanes bit-equal)

    float mr = m0, mi = -1.0f;
    float qre[CPN], qim[CPN];

    for (int it = 0; it < NITER; ++it) {
        // ---- S = sum_k wt_tau_k / (tau_k*m - x): 16 independent divides ----
        #pragma unroll
        for (int s = 0; s < CPN; ++s) {
            float dr = tauC[s] * mr - xv;   // mul, sub (no fma)
            float di = tauC[s] * mi;
            cdiv_nr(wttC[s], dr, di, qre[s], qim[s]);
        }
        // numpy chain on accumulator lanes 0-3 (lanes 4-7 compute garbage,
        // corrected by the broadcast): self q[s] (t=2s) then pulled (t=2s+1).
        float sre = 0.0f, sim = 0.0f;
        #pragma unroll
        for (int s = 0; s < CPN; ++s) {
            float pre = PULL4(qre[s]);
            float pim = PULL4(qim[s]);
            sre = (s == 0) ? qre[0] : (sre + qre[s]);
            sim = (s == 0) ? qim[0] : (sim + qim[s]);
            sre += pre;
            sim += pim;
        }
        RED4(sre);
        RED4(sim);
        sre = __shfl(sre, 0, 8);   // broadcast acc-combined value to all 8 lanes
        sim = __shfl(sim, 0, 8);

        // ---- F = sum_j wd_d_j / (1 + (c*d_j)*S) ----
        #pragma unroll
        for (int s = 0; s < CPN; ++s) {
            float er = 1.0f + cdC[s] * sre;  // mul, add (no fma)
            float ei = cdC[s] * sim;
            cdiv_nr(wddC[s], er, ei, qre[s], qim[s]);
        }
        float fre = 0.0f, fim = 0.0f;
        #pragma unroll
        for (int s = 0; s < CPN; ++s) {
            float pre = PULL4(qre[s]);
            float pim = PULL4(qim[s]);
            fre = (s == 0) ? qre[0] : (fre + qre[s]);
            fim = (s == 0) ? qim[0] : (fim + qim[s]);
            fre += pre;
            fim += pim;
        }
        RED4(fre);
        RED4(fim);
        fre = __shfl(fre, 0, 8);
        fim = __shfl(fim, 0, 8);

        float mnre = fre;
        float mnim = fminf(fim, -1e-10f);   // Im < 0 branch clamp
        mr = 0.5f * mr + 0.5f * mnre;       // exact halvings + one add round
        mi = 0.5f * mi + 0.5f * mnim;
    }

    // ---- m(x) = sum_k wt_k / (tau_k*m_tilde - x), same structure ----
    #pragma unroll
    for (int s = 0; s < CPN; ++s) {
        float dr = tauC[s] * mr - xv;
        float di = tauC[s] * mi;
        cdiv_nr(wtC[s], dr, di, qre[s], qim[s]);
    }
    float ore = 0.0f, oim = 0.0f;
    #pragma unroll
    for (int s = 0; s < CPN; ++s) {
        float pre = PULL4(qre[s]);
        float pim = PULL4(qim[s]);
        ore = (s == 0) ? qre[0] : (ore + qre[s]);
        oim = (s == 0) ? qim[0] : (oim + qim[s]);
        ore += pre;
        oim += pim;
    }
    RED4(ore);
    RED4(oim);

    if (L == 0) {
        // Layout (verified passing R7-R15): [f | m.real | X.real], 24576 floats.
        out[gid]           = (float)((double)fabsf(oim) / 3.141592653589793);
        out[NXP + gid]     = ore;
        float scl = div_ieee(1.0f, xv);         // Smith with zero-imag denom
        out[2 * NXP + gid] = -mr * scl;         // X.real
    }
}

extern "C" void kernel_launch(void* const* d_in, const int* in_sizes, int n_in,
                              void* d_out, int out_size, void* d_ws, size_t ws_size,
                              hipStream_t stream) {
    const float* x   = (const float*)d_in[0];
    const float* d   = (const float*)d_in[1];
    const float* wd  = (const float*)d_in[2];
    const float* tau = (const float*)d_in[3];
    const float* wt  = (const float*)d_in[4];
    float* out = (float*)d_out;

    // 128 threads/block = 16 points/block -> 512 blocks = 2 blocks/CU,
    // 4 waves/CU -> 1024 waves total: one wave on EVERY SIMD (was 512/half).
    const int pts_per_block = 128 / GROUP;
    const int nblocks = NXP / pts_per_block;
    wesper_kernel<<<nblocks, 128, 0, stream>>>(x, d, wd, tau, wt, out);
}